// Round 7
// baseline (50.924 us; speedup 1.0000x reference)
//
#include <hip/hip_runtime.h>

#define T_FRAMES 100
#define R_REP    8
#define N_ATOMS  83
#define N_BINS   120
#define NPAIRS   (N_ATOMS * (N_ATOMS - 1) / 2)   // 3403
#define BLK      256
#define PPT      7          // pairs per thread: 256*7=1792 >= 1702
#define HALF0    1702       // pairs in block-half 0 (half 1 gets 1701)
#define NBLOCKS  (2 * T_FRAMES * R_REP)          // 1600

__device__ __forceinline__ int rowstart(int i) {
    // upper-triangle (i<j) row start for N=83: i*(165-i)/2
    return (i * (165 - i)) >> 1;
}

// ---- fused kernel: min-image hist (all blocks) + finalize (last block) ----
// ws layout: [0..959] hist u32 ([R][N_BINS]), [960] done-counter.
// hist+counter are zeroed by a memset node each launch.
__global__ __launch_bounds__(BLK, 4) void rdf_fused_kernel(
        const float* __restrict__ radii,    // [T, R, N, 3]
        const float* __restrict__ cell,     // [3, 3]
        const float* __restrict__ bins,     // [N_BINS+1]
        const float* __restrict__ gt,       // [N_BINS]
        unsigned int* __restrict__ ws,      // hist + counter
        float* __restrict__ out)            // [R*N_BINS + R]
{
#pragma clang fp contract(off)
    __shared__ float sx[N_ATOMS], sy[N_ATOMS], sz[N_ATOMS];
    __shared__ float scell[12];            // rows padded to 4
    __shared__ float sbins[N_BINS + 1];
    __shared__ unsigned int shist[N_BINS];
    __shared__ int slast;
    __shared__ float sdiff[R_REP][N_BINS];

    unsigned int* __restrict__ hist_g = ws;          // [R][N_BINS]
    unsigned int* __restrict__ cnt    = ws + R_REP * N_BINS;

    const int tid  = threadIdx.x;
    const int blk  = blockIdx.x;           // 0 .. NBLOCKS-1
    const int fr   = blk >> 1;             // frame index 0..799
    const int half = blk & 1;
    const int t = fr / R_REP;
    const int r = fr % R_REP;
    const int pstart = half ? HALF0 : 0;
    const int pcount = half ? (NPAIRS - HALF0) : HALF0;

    // stage this frame's atoms (SoA)
    for (int i = tid; i < N_ATOMS; i += BLK) {
        const float* p = radii + (((size_t)t * R_REP + r) * N_ATOMS + i) * 3;
        sx[i] = p[0]; sy[i] = p[1]; sz[i] = p[2];
    }
    for (int i = tid; i <= N_BINS; i += BLK) sbins[i] = bins[i];
    for (int i = tid; i < N_BINS; i += BLK) shist[i] = 0u;
    if (tid < 9) scell[(tid / 3) * 4 + (tid % 3)] = cell[tid];
    __syncthreads();

    // cell rows -> registers (broadcast reads)
    float cc[3][3];
#pragma unroll
    for (int q = 0; q < 3; ++q)
#pragma unroll
        for (int d = 0; d < 3; ++d) cc[q][d] = scell[q * 4 + d];
    float rn[3];   // reciprocal row-norms (selection only)
#pragma unroll
    for (int q = 0; q < 3; ++q)
        rn[q] = 1.0f / (cc[q][0] * cc[q][0] + cc[q][1] * cc[q][1] + cc[q][2] * cc[q][2]);

    // ---- load phase: resolve PPT pairs per thread into registers ----------
    float dx[PPT], dy[PPT], dz[PPT], d2m[PPT];
#pragma unroll
    for (int s = 0; s < PPT; ++s) {
        const int l = tid + s * BLK;
        const int p = (l < pcount) ? (pstart + l) : 0;
        int i = (int)((165.0f - sqrtf((float)(27225 - 8 * p))) * 0.5f);
        if (i < 0) i = 0;
        if (i > N_ATOMS - 2) i = N_ATOMS - 2;
        while (rowstart(i + 1) <= p) ++i;
        while (rowstart(i) > p) --i;
        const int j = p - rowstart(i) + i + 1;
        dx[s] = sx[i] - sx[j];
        dy[s] = sy[i] - sy[j];
        dz[s] = sz[i] - sz[j];
        d2m[s] = 3.4e38f;
    }

    // ---- 8-candidate exact min-image (argmin provably in {floor,floor+1}^3)
#pragma unroll
    for (int s = 0; s < PPT; ++s) {
        const float Dx = dx[s], Dy = dy[s], Dz = dz[s];
        const float fx = (Dx * cc[0][0] + Dy * cc[0][1] + Dz * cc[0][2]) * rn[0];
        const float fy = (Dx * cc[1][0] + Dy * cc[1][1] + Dz * cc[1][2]) * rn[1];
        const float fz = (Dx * cc[2][0] + Dy * cc[2][1] + Dz * cc[2][2]) * rn[2];
        int axi = (int)floorf(fx); axi = axi < -1 ? -1 : (axi > 0 ? 0 : axi);
        int ayi = (int)floorf(fy); ayi = ayi < -1 ? -1 : (ayi > 0 ? 0 : ayi);
        int azi = (int)floorf(fz); azi = azi < -1 ? -1 : (azi > 0 ? 0 : azi);
        const float na0 = (float)axi, na1 = na0 + 1.0f;
        const float nb0 = (float)ayi, nb1 = nb0 + 1.0f;
        const float nc0 = (float)azi, nc1 = nc0 + 1.0f;

        float An[2][3], Bn[2][3], Cn[2][3];   // exact products n*cell_row
#pragma unroll
        for (int d = 0; d < 3; ++d) {
            An[0][d] = na0 * cc[0][d]; An[1][d] = na1 * cc[0][d];
            Bn[0][d] = nb0 * cc[1][d]; Bn[1][d] = nb1 * cc[1][d];
            Cn[0][d] = nc0 * cc[2][d]; Cn[1][d] = nc1 * cc[2][d];
        }
        float m = d2m[s];
#pragma unroll
        for (int ia = 0; ia < 2; ++ia) {
#pragma unroll
            for (int ib = 0; ib < 2; ++ib) {
                const float m0 = An[ia][0] + Bn[ib][0];   // reference's 1st add
                const float m1 = An[ia][1] + Bn[ib][1];
                const float m2 = An[ia][2] + Bn[ib][2];
#pragma unroll
                for (int ic = 0; ic < 2; ++ic) {
                    const float t0 = Dx - (m0 + Cn[ic][0]);  // 2nd add, then sub
                    const float t1 = Dy - (m1 + Cn[ic][1]);
                    const float t2 = Dz - (m2 + Cn[ic][2]);
                    const float d2 = (t0 * t0 + t1 * t1) + t2 * t2;  // contract off
                    m = fminf(m, d2);
                }
            }
        }
        d2m[s] = m;
    }

    // ---- binning phase -----------------------------------------------------
    const float blo = sbins[0];
    const float bhi = sbins[N_BINS];
    const float inv_step = (float)N_BINS / (bhi - blo);
#pragma unroll
    for (int s = 0; s < PPT; ++s) {
        const int l = tid + s * BLK;
        if (l >= pcount) continue;
        const float d = sqrtf(d2m[s]);             // IEEE-correct
        if (d >= blo && d <= bhi) {
            int idx = (int)((d - blo) * inv_step);
            if (idx > N_BINS - 1) idx = N_BINS - 1;
            if (idx < 0) idx = 0;
            while (idx > 0 && d < sbins[idx]) --idx;
            while (idx < N_BINS - 1 && d >= sbins[idx + 1]) ++idx;
            atomicAdd(&shist[idx], 2u);            // (i,j)/(j,i) bit-identical
        }
    }
    __syncthreads();

    // ---- flush: device-scope atomics into global hist (coherent) ----------
    if (tid < N_BINS) {
        const unsigned int v = shist[tid];
        if (v) atomicAdd(&hist_g[r * N_BINS + tid], v);
    }
    __syncthreads();   // drains this block's atomics (vmcnt(0) before barrier)

    // ---- last-block-done: only the final arriver finalizes ----------------
    if (tid == 0) {
        __threadfence();
        const unsigned int old = atomicAdd(cnt, 1u);
        slast = (old == NBLOCKS - 1) ? 1 : 0;
    }
    __syncthreads();
    if (!slast) return;
    __threadfence();   // acquire: all blocks' hist atomics visible

    // ---- finalize: rdf = hist/Z, out, per-replica MAE ---------------------
    const float c0x = cc[0][0], c0y = cc[0][1], c0z = cc[0][2];
    const float c1x = cc[1][0], c1y = cc[1][1], c1z = cc[1][2];
    const float c2x = cc[2][0], c2y = cc[2][1], c2z = cc[2][2];
    const float crx = c0y * c1z - c0z * c1y;
    const float cry = c0z * c1x - c0x * c1z;
    const float crz = c0x * c1y - c0y * c1x;
    const float vol = fabsf(crx * c2x + cry * c2y + crz * c2z);
    const float rho = (float)(T_FRAMES * N_ATOMS * N_ATOMS) / vol;
    const float coef = (rho * 1.33333337f) * 3.14159274f;  // rho * 4/3 * pi

    for (int e = tid; e < R_REP * N_BINS; e += BLK) {
        const int b = e % N_BINS;
        const unsigned int tot =
            __hip_atomic_load(&hist_g[e], __ATOMIC_RELAXED, __HIP_MEMORY_SCOPE_AGENT);
        const float b1 = sbins[b], b2 = sbins[b + 1];
        const float Z = coef * (b2 * b2 * b2 - b1 * b1 * b1);
        const float v = (float)tot / Z;
        out[e] = v;
        sdiff[e / N_BINS][b] = fabsf(v - gt[b]);
    }
    __syncthreads();

    // 4 waves, each reduces 2 replicas: lane l holds sdiff[rr][l]+sdiff[rr][l+64]
    const int wave = tid >> 6;
    const int lane = tid & 63;
#pragma unroll
    for (int w = 0; w < 2; ++w) {
        const int rr = wave * 2 + w;
        float s = sdiff[rr][lane] + ((lane < N_BINS - 64) ? sdiff[rr][lane + 64] : 0.0f);
#pragma unroll
        for (int off = 32; off; off >>= 1) s += __shfl_down(s, off, 64);
        if (lane == 0)
            out[R_REP * N_BINS + rr] = 6.0f * (s * (1.0f / (float)N_BINS));
    }
}

extern "C" void kernel_launch(void* const* d_in, const int* in_sizes, int n_in,
                              void* d_out, int out_size, void* d_ws, size_t ws_size,
                              hipStream_t stream) {
    const float* radii = (const float*)d_in[0];  // [100,8,83,3]
    const float* cell  = (const float*)d_in[1];  // [3,3]
    const float* gt    = (const float*)d_in[2];  // [120]
    const float* bins  = (const float*)d_in[3];  // [121]
    float* out = (float*)d_out;                  // 8*120 rdfs + 8 maes
    unsigned int* ws   = (unsigned int*)d_ws;    // [960] hist + [1] counter

    hipMemsetAsync(ws, 0, (R_REP * N_BINS + 1) * sizeof(unsigned int), stream);
    hipLaunchKernelGGL(rdf_fused_kernel, dim3(NBLOCKS), dim3(BLK), 0, stream,
                       radii, cell, bins, gt, ws, out);
}

// Round 8
// 29.142 us; speedup vs baseline: 1.7475x; 1.7475x over previous
//
#include <hip/hip_runtime.h>

#define T_FRAMES 100
#define R_REP    8
#define N_ATOMS  83
#define N_BINS   120
#define NPAIRS   (N_ATOMS * (N_ATOMS - 1) / 2)   // 3403
#define BLK      256
#define PPT      4          // pairs per thread: 256*4=1024 >= 851
#define QPF      4          // blocks per frame
#define QSIZE    851        // ceil(NPAIRS/QPF)
#define SLOTS    (T_FRAMES * QPF)                // 400 partial hists per replica

__device__ __forceinline__ int rowstart(int i) {
    // upper-triangle (i<j) row start for N=83: i*(165-i)/2
    return (i * (165 - i)) >> 1;
}

// ---------------- kernel 1: min-image distances + per-block partial hist ---
// QPF blocks per (frame t, replica r). 8-candidate exact min-image search:
// argmin over the 27-box provably lies in {floor(f~),floor(f~)+1}^3 (curvature
// ~104 A^2 vs coupling ~4 A^2); each candidate d2 uses the reference's exact
// fp32 chain, so min over 8 == min over 27 bit-exactly (verified r6: absmax
// identical to the 27-shift version).
__global__ __launch_bounds__(BLK, 8) void rdf_hist_kernel(
        const float* __restrict__ radii,    // [T, R, N, 3]
        const float* __restrict__ cell,     // [3, 3]
        const float* __restrict__ bins,     // [N_BINS+1]
        unsigned int* __restrict__ partial) // [R, SLOTS, N_BINS]
{
#pragma clang fp contract(off)
    __shared__ float sx[N_ATOMS], sy[N_ATOMS], sz[N_ATOMS];
    __shared__ float scell[12];            // rows padded to 4
    __shared__ float sbins[N_BINS + 1];
    __shared__ unsigned int shist[N_BINS];

    const int tid = threadIdx.x;
    const int blk = blockIdx.x;            // 0 .. QPF*T*R-1
    const int fr  = blk >> 2;              // frame index 0..799
    const int q   = blk & 3;
    const int t = fr / R_REP;
    const int r = fr % R_REP;
    const int pstart = q * QSIZE;
    const int pcount = (q == QPF - 1) ? (NPAIRS - pstart) : QSIZE;

    // stage this frame's atoms (SoA)
    for (int i = tid; i < N_ATOMS; i += BLK) {
        const float* p = radii + (((size_t)t * R_REP + r) * N_ATOMS + i) * 3;
        sx[i] = p[0]; sy[i] = p[1]; sz[i] = p[2];
    }
    for (int i = tid; i <= N_BINS; i += BLK) sbins[i] = bins[i];
    for (int i = tid; i < N_BINS; i += BLK) shist[i] = 0u;
    if (tid < 9) scell[(tid / 3) * 4 + (tid % 3)] = cell[tid];
    __syncthreads();

    // cell rows -> registers (broadcast reads)
    float cc[3][3];
#pragma unroll
    for (int c = 0; c < 3; ++c)
#pragma unroll
        for (int d = 0; d < 3; ++d) cc[c][d] = scell[c * 4 + d];
    float rn[3];   // reciprocal row-norms (candidate selection only)
#pragma unroll
    for (int c = 0; c < 3; ++c)
        rn[c] = 1.0f / (cc[c][0] * cc[c][0] + cc[c][1] * cc[c][1] + cc[c][2] * cc[c][2]);

    // ---- load phase: resolve PPT pairs per thread into registers ----------
    float dx[PPT], dy[PPT], dz[PPT], d2m[PPT];
#pragma unroll
    for (int s = 0; s < PPT; ++s) {
        const int l = tid + s * BLK;
        const int p = (l < pcount) ? (pstart + l) : 0;
        int i = (int)((165.0f - sqrtf((float)(27225 - 8 * p))) * 0.5f);
        if (i < 0) i = 0;
        if (i > N_ATOMS - 2) i = N_ATOMS - 2;
        while (rowstart(i + 1) <= p) ++i;
        while (rowstart(i) > p) --i;
        const int j = p - rowstart(i) + i + 1;
        dx[s] = sx[i] - sx[j];
        dy[s] = sy[i] - sy[j];
        dz[s] = sz[i] - sz[j];
        d2m[s] = 3.4e38f;
    }

    // ---- 8-candidate exact min-image, pure register math ------------------
#pragma unroll
    for (int s = 0; s < PPT; ++s) {
        const float Dx = dx[s], Dy = dy[s], Dz = dz[s];
        const float fx = (Dx * cc[0][0] + Dy * cc[0][1] + Dz * cc[0][2]) * rn[0];
        const float fy = (Dx * cc[1][0] + Dy * cc[1][1] + Dz * cc[1][2]) * rn[1];
        const float fz = (Dx * cc[2][0] + Dy * cc[2][1] + Dz * cc[2][2]) * rn[2];
        int axi = (int)floorf(fx); axi = axi < -1 ? -1 : (axi > 0 ? 0 : axi);
        int ayi = (int)floorf(fy); ayi = ayi < -1 ? -1 : (ayi > 0 ? 0 : ayi);
        int azi = (int)floorf(fz); azi = azi < -1 ? -1 : (azi > 0 ? 0 : azi);
        const float na0 = (float)axi, na1 = na0 + 1.0f;
        const float nb0 = (float)ayi, nb1 = nb0 + 1.0f;
        const float nc0 = (float)azi, nc1 = nc0 + 1.0f;

        float An[2][3], Bn[2][3], Cn[2][3];   // exact products n*cell_row
#pragma unroll
        for (int d = 0; d < 3; ++d) {
            An[0][d] = na0 * cc[0][d]; An[1][d] = na1 * cc[0][d];
            Bn[0][d] = nb0 * cc[1][d]; Bn[1][d] = nb1 * cc[1][d];
            Cn[0][d] = nc0 * cc[2][d]; Cn[1][d] = nc1 * cc[2][d];
        }
        float m = d2m[s];
#pragma unroll
        for (int ia = 0; ia < 2; ++ia) {
#pragma unroll
            for (int ib = 0; ib < 2; ++ib) {
                const float m0 = An[ia][0] + Bn[ib][0];   // reference's 1st add
                const float m1 = An[ia][1] + Bn[ib][1];
                const float m2 = An[ia][2] + Bn[ib][2];
#pragma unroll
                for (int ic = 0; ic < 2; ++ic) {
                    const float t0 = Dx - (m0 + Cn[ic][0]);  // 2nd add, then sub
                    const float t1 = Dy - (m1 + Cn[ic][1]);
                    const float t2 = Dz - (m2 + Cn[ic][2]);
                    const float d2 = (t0 * t0 + t1 * t1) + t2 * t2;  // contract off
                    m = fminf(m, d2);
                }
            }
        }
        d2m[s] = m;
    }

    // ---- binning phase -----------------------------------------------------
    const float blo = sbins[0];
    const float inv_step = (float)N_BINS / (6.0f - blo);
#pragma unroll
    for (int s = 0; s < PPT; ++s) {
        const int l = tid + s * BLK;
        if (l >= pcount) continue;
        // d2 > 36.0f  <=>  sqrtf(d2) > 6.0f exactly (sqrt monotone, 6.0/36.0
        // exact fp32; ulp-neighbors of 36 round strictly across 6.0)
        if (d2m[s] > 36.0f) continue;
        const float d = sqrtf(d2m[s]);             // IEEE-correct
        if (d >= blo) {
            int idx = (int)((d - blo) * inv_step);
            if (idx > N_BINS - 1) idx = N_BINS - 1;
            if (idx < 0) idx = 0;
            while (idx > 0 && d < sbins[idx]) --idx;
            while (idx < N_BINS - 1 && d >= sbins[idx + 1]) ++idx;
            atomicAdd(&shist[idx], 2u);            // (i,j)/(j,i) bit-identical
        }
    }
    __syncthreads();

    // ---- flush partial hist (plain stores; no zeroed global needed) -------
    unsigned int* dst = partial + ((size_t)((r * T_FRAMES + t) * QPF + q)) * N_BINS;
    for (int b = tid; b < N_BINS; b += BLK) dst[b] = shist[b];
}

// ---------------- kernel 2: reduce partials, rdf = hist/Z, maes ------------
// One block per replica. 512 threads, 4 slot-chunks of 100.
__global__ __launch_bounds__(512) void finalize_kernel(
        const unsigned int* __restrict__ partial, // [R, SLOTS, N_BINS]
        const float* __restrict__ cell,
        const float* __restrict__ bins,
        const float* __restrict__ gt,             // [N_BINS]
        float* __restrict__ out)                  // [R*N_BINS + R]
{
    __shared__ unsigned int ssum[4][N_BINS];
    __shared__ float sdiff[N_BINS];
    const int r = blockIdx.x;
    const int tid = threadIdx.x;
    const int h = tid >> 7;          // 0..3: which 100-slot chunk
    const int b = tid & 127;

    if (b < N_BINS) {
        const unsigned int* base = partial
            + (size_t)r * SLOTS * N_BINS + (size_t)h * 100 * N_BINS + b;
        unsigned int acc = 0;
#pragma unroll 20
        for (int f = 0; f < 100; ++f) acc += base[(size_t)f * N_BINS];
        ssum[h][b] = acc;
    }
    __syncthreads();

    const float c0x = cell[0], c0y = cell[1], c0z = cell[2];
    const float c1x = cell[3], c1y = cell[4], c1z = cell[5];
    const float c2x = cell[6], c2y = cell[7], c2z = cell[8];
    const float crx = c0y * c1z - c0z * c1y;
    const float cry = c0z * c1x - c0x * c1z;
    const float crz = c0x * c1y - c0y * c1x;
    const float vol = fabsf(crx * c2x + cry * c2y + crz * c2z);
    const float rho = (float)(T_FRAMES * N_ATOMS * N_ATOMS) / vol;
    const float coef = (rho * 1.33333337f) * 3.14159274f;  // rho * 4/3 * pi

    if (tid < N_BINS) {
        const unsigned int tot = ssum[0][tid] + ssum[1][tid] + ssum[2][tid] + ssum[3][tid];
        const float b1 = bins[tid], b2 = bins[tid + 1];
        const float Z = coef * (b2 * b2 * b2 - b1 * b1 * b1);
        const float v = (float)tot / Z;
        out[r * N_BINS + tid] = v;
        sdiff[tid] = fabsf(v - gt[tid]);
    }
    __syncthreads();

    if (tid < 64) {
        float s = sdiff[tid] + ((tid < N_BINS - 64) ? sdiff[tid + 64] : 0.0f);
#pragma unroll
        for (int off = 32; off; off >>= 1) s += __shfl_down(s, off, 64);
        if (tid == 0)
            out[R_REP * N_BINS + r] = 6.0f * (s * (1.0f / (float)N_BINS));
    }
}

extern "C" void kernel_launch(void* const* d_in, const int* in_sizes, int n_in,
                              void* d_out, int out_size, void* d_ws, size_t ws_size,
                              hipStream_t stream) {
    const float* radii = (const float*)d_in[0];  // [100,8,83,3]
    const float* cell  = (const float*)d_in[1];  // [3,3]
    const float* gt    = (const float*)d_in[2];  // [120]
    const float* bins  = (const float*)d_in[3];  // [121]
    float* out = (float*)d_out;                  // 8*120 rdfs + 8 maes
    unsigned int* part = (unsigned int*)d_ws;    // [8][400][120] u32 = 1.5 MB

    hipLaunchKernelGGL(rdf_hist_kernel, dim3(QPF * T_FRAMES * R_REP), dim3(BLK), 0, stream,
                       radii, cell, bins, part);
    hipLaunchKernelGGL(finalize_kernel, dim3(R_REP), dim3(512), 0, stream,
                       part, cell, bins, gt, out);
}

// Round 9
// 27.500 us; speedup vs baseline: 1.8518x; 1.0597x over previous
//
#include <hip/hip_runtime.h>

#define T_FRAMES 100
#define R_REP    8
#define N_ATOMS  83
#define N_BINS   120
#define NWORDS   60          // N_BINS/2 packed u16 pairs
#define NPAIRS   (N_ATOMS * (N_ATOMS - 1) / 2)   // 3403
#define BLK      256
#define PPT      7           // pairs per thread: 256*7=1792 >= 1702
#define HALF0    1702        // pairs in block-half 0 (half 1 gets 1701)
#define SLOTS    (2 * T_FRAMES)                  // 200 partial hists per replica

__device__ __forceinline__ int rowstart(int i) {
    // upper-triangle (i<j) row start for N=83: i*(165-i)/2
    return (i * (165 - i)) >> 1;
}

// ---------------- kernel 1: min-image distances + per-block partial hist ---
// Two blocks per (frame t, replica r). 8-candidate exact min-image search:
// argmin over the 27-box provably lies in {floor(f~),floor(f~)+1}^3 (curvature
// ~104 A^2 vs coupling ~4 A^2, ~12x margin); each candidate d2 uses the
// reference's exact fp32 chain, so min over 8 == min over 27 bit-exactly
// (verified r6/r8: absmax identical to the 27-shift version).
__global__ __launch_bounds__(BLK, 4) void rdf_hist_kernel(
        const float* __restrict__ radii,    // [T, R, N, 3]
        const float* __restrict__ cell,     // [3, 3]
        const float* __restrict__ bins,     // [N_BINS+1]
        unsigned int* __restrict__ partial) // [R, SLOTS, NWORDS] packed u16x2
{
#pragma clang fp contract(off)
    __shared__ float sx[N_ATOMS], sy[N_ATOMS], sz[N_ATOMS];
    __shared__ float sfx[N_ATOMS], sfy[N_ATOMS], sfz[N_ATOMS];
    __shared__ float sbins[N_BINS + 1];
    __shared__ unsigned int shist[N_BINS];

    const int tid  = threadIdx.x;
    const int blk  = blockIdx.x;           // 0 .. 2*T*R-1
    const int fr   = blk >> 1;             // frame index 0..799
    const int half = blk & 1;
    const int t = fr / R_REP;
    const int r = fr % R_REP;
    const int pstart = half ? HALF0 : 0;
    const int pcount = half ? (NPAIRS - HALF0) : HALF0;

    // cell rows -> registers via uniform (scalar) loads; no LDS staging
    float cc[3][3];
#pragma unroll
    for (int c = 0; c < 3; ++c)
#pragma unroll
        for (int d = 0; d < 3; ++d) cc[c][d] = cell[c * 3 + d];
    float rn[3];   // reciprocal row-norms (candidate selection only)
#pragma unroll
    for (int c = 0; c < 3; ++c)
        rn[c] = 1.0f / (cc[c][0] * cc[c][0] + cc[c][1] * cc[c][1] + cc[c][2] * cc[c][2]);

    // stage this frame's atoms (SoA) + per-atom fractional coords (selection only)
    for (int i = tid; i < N_ATOMS; i += BLK) {
        const float* p = radii + (((size_t)t * R_REP + r) * N_ATOMS + i) * 3;
        const float x = p[0], y = p[1], z = p[2];
        sx[i] = x; sy[i] = y; sz[i] = z;
        sfx[i] = (x * cc[0][0] + y * cc[0][1] + z * cc[0][2]) * rn[0];
        sfy[i] = (x * cc[1][0] + y * cc[1][1] + z * cc[1][2]) * rn[1];
        sfz[i] = (x * cc[2][0] + y * cc[2][1] + z * cc[2][2]) * rn[2];
    }
    for (int i = tid; i <= N_BINS; i += BLK) sbins[i] = bins[i];
    for (int i = tid; i < N_BINS; i += BLK) shist[i] = 0u;
    __syncthreads();

    // ---- load phase: resolve PPT pairs per thread into registers ----------
    float dx[PPT], dy[PPT], dz[PPT], fx[PPT], fy[PPT], fz[PPT];
#pragma unroll
    for (int s = 0; s < PPT; ++s) {
        const int l = tid + s * BLK;
        const int p = (l < pcount) ? (pstart + l) : 0;
        int i = (int)((165.0f - sqrtf((float)(27225 - 8 * p))) * 0.5f);
        if (i < 0) i = 0;
        if (i > N_ATOMS - 2) i = N_ATOMS - 2;
        while (rowstart(i + 1) <= p) ++i;
        while (rowstart(i) > p) --i;
        const int j = p - rowstart(i) + i + 1;
        dx[s] = sx[i] - sx[j];
        dy[s] = sy[i] - sy[j];
        dz[s] = sz[i] - sz[j];
        fx[s] = sfx[i] - sfx[j];
        fy[s] = sfy[i] - sfy[j];
        fz[s] = sfz[i] - sfz[j];
    }

    float d2m[PPT];
    // ---- 8-candidate exact min-image, pure register math ------------------
#pragma unroll
    for (int s = 0; s < PPT; ++s) {
        const float Dx = dx[s], Dy = dy[s], Dz = dz[s];
        int axi = (int)floorf(fx[s]); axi = axi < -1 ? -1 : (axi > 0 ? 0 : axi);
        int ayi = (int)floorf(fy[s]); ayi = ayi < -1 ? -1 : (ayi > 0 ? 0 : ayi);
        int azi = (int)floorf(fz[s]); azi = azi < -1 ? -1 : (azi > 0 ? 0 : azi);
        const float na0 = (float)axi, na1 = na0 + 1.0f;
        const float nb0 = (float)ayi, nb1 = nb0 + 1.0f;
        const float nc0 = (float)azi, nc1 = nc0 + 1.0f;

        float An[2][3], Bn[2][3], Cn[2][3];   // exact products n*cell_row
#pragma unroll
        for (int d = 0; d < 3; ++d) {
            An[0][d] = na0 * cc[0][d]; An[1][d] = na1 * cc[0][d];
            Bn[0][d] = nb0 * cc[1][d]; Bn[1][d] = nb1 * cc[1][d];
            Cn[0][d] = nc0 * cc[2][d]; Cn[1][d] = nc1 * cc[2][d];
        }
        float m = 3.4e38f;
#pragma unroll
        for (int ia = 0; ia < 2; ++ia) {
#pragma unroll
            for (int ib = 0; ib < 2; ++ib) {
                const float m0 = An[ia][0] + Bn[ib][0];   // reference's 1st add
                const float m1 = An[ia][1] + Bn[ib][1];
                const float m2 = An[ia][2] + Bn[ib][2];
#pragma unroll
                for (int ic = 0; ic < 2; ++ic) {
                    const float t0 = Dx - (m0 + Cn[ic][0]);  // 2nd add, then sub
                    const float t1 = Dy - (m1 + Cn[ic][1]);
                    const float t2 = Dz - (m2 + Cn[ic][2]);
                    const float d2 = (t0 * t0 + t1 * t1) + t2 * t2;  // contract off
                    m = fminf(m, d2);
                }
            }
        }
        d2m[s] = m;
    }

    // ---- binning phase -----------------------------------------------------
    const float blo = sbins[0];
    const float inv_step = (float)N_BINS / (6.0f - blo);
#pragma unroll
    for (int s = 0; s < PPT; ++s) {
        const int l = tid + s * BLK;
        if (l >= pcount) continue;
        // d2 > 36.0f <=> sqrtf(d2) > 6.0f exactly (sqrt monotone; 6, 36 exact)
        if (d2m[s] > 36.0f) continue;
        const float d = sqrtf(d2m[s]);             // IEEE-correct
        if (d >= blo) {
            int idx = (int)((d - blo) * inv_step);
            if (idx > N_BINS - 1) idx = N_BINS - 1;
            if (idx < 0) idx = 0;
            while (idx > 0 && d < sbins[idx]) --idx;
            while (idx < N_BINS - 1 && d >= sbins[idx + 1]) ++idx;
            atomicAdd(&shist[idx], 2u);            // (i,j)/(j,i) bit-identical
        }
    }
    __syncthreads();

    // ---- flush packed partial hist (plain stores; counts <= 3404 < 2^16) --
    if (tid < NWORDS) {
        const unsigned int w = shist[2 * tid] | (shist[2 * tid + 1] << 16);
        partial[((size_t)(r * SLOTS + t * 2 + half)) * NWORDS + tid] = w;
    }
}

// ---------------- kernel 2: reduce partials, rdf = hist/Z, maes ------------
// One block per replica. 256 threads: 4 chunks x 64 lanes (60 active).
__global__ __launch_bounds__(256) void finalize_kernel(
        const unsigned int* __restrict__ partial, // [R, SLOTS, NWORDS]
        const float* __restrict__ cell,
        const float* __restrict__ bins,
        const float* __restrict__ gt,             // [N_BINS]
        float* __restrict__ out)                  // [R*N_BINS + R]
{
    __shared__ unsigned int slo[4][NWORDS], shi[4][NWORDS];
    __shared__ float sdiff[N_BINS];
    const int r = blockIdx.x;
    const int tid = threadIdx.x;
    const int h = tid >> 6;          // 0..3: which 50-slot chunk
    const int c = tid & 63;          // word index, active c < NWORDS

    if (c < NWORDS) {
        const unsigned int* base = partial
            + (size_t)r * SLOTS * NWORDS + (size_t)h * 50 * NWORDS + c;
        unsigned int lo = 0, hi = 0;
#pragma unroll 10
        for (int f = 0; f < 50; ++f) {
            const unsigned int w = base[(size_t)f * NWORDS];
            lo += w & 0xFFFFu;
            hi += w >> 16;
        }
        slo[h][c] = lo;
        shi[h][c] = hi;
    }
    __syncthreads();

    const float c0x = cell[0], c0y = cell[1], c0z = cell[2];
    const float c1x = cell[3], c1y = cell[4], c1z = cell[5];
    const float c2x = cell[6], c2y = cell[7], c2z = cell[8];
    const float crx = c0y * c1z - c0z * c1y;
    const float cry = c0z * c1x - c0x * c1z;
    const float crz = c0x * c1y - c0y * c1x;
    const float vol = fabsf(crx * c2x + cry * c2y + crz * c2z);
    const float rho = (float)(T_FRAMES * N_ATOMS * N_ATOMS) / vol;
    const float coef = (rho * 1.33333337f) * 3.14159274f;  // rho * 4/3 * pi

    if (tid < N_BINS) {
        const int w = tid >> 1;
        unsigned int tot = 0;
        if (tid & 1) tot = shi[0][w] + shi[1][w] + shi[2][w] + shi[3][w];
        else         tot = slo[0][w] + slo[1][w] + slo[2][w] + slo[3][w];
        const float b1 = bins[tid], b2 = bins[tid + 1];
        const float Z = coef * (b2 * b2 * b2 - b1 * b1 * b1);
        const float v = (float)tot / Z;
        out[r * N_BINS + tid] = v;
        sdiff[tid] = fabsf(v - gt[tid]);
    }
    __syncthreads();

    if (tid < 64) {
        float s = sdiff[tid] + ((tid < N_BINS - 64) ? sdiff[tid + 64] : 0.0f);
#pragma unroll
        for (int off = 32; off; off >>= 1) s += __shfl_down(s, off, 64);
        if (tid == 0)
            out[R_REP * N_BINS + r] = 6.0f * (s * (1.0f / (float)N_BINS));
    }
}

extern "C" void kernel_launch(void* const* d_in, const int* in_sizes, int n_in,
                              void* d_out, int out_size, void* d_ws, size_t ws_size,
                              hipStream_t stream) {
    const float* radii = (const float*)d_in[0];  // [100,8,83,3]
    const float* cell  = (const float*)d_in[1];  // [3,3]
    const float* gt    = (const float*)d_in[2];  // [120]
    const float* bins  = (const float*)d_in[3];  // [121]
    float* out = (float*)d_out;                  // 8*120 rdfs + 8 maes
    unsigned int* part = (unsigned int*)d_ws;    // [8][200][60] u32 = 384 KB

    hipLaunchKernelGGL(rdf_hist_kernel, dim3(2 * T_FRAMES * R_REP), dim3(BLK), 0, stream,
                       radii, cell, bins, part);
    hipLaunchKernelGGL(finalize_kernel, dim3(R_REP), dim3(256), 0, stream,
                       part, cell, bins, gt, out);
}